// Round 3
// baseline (713.364 us; speedup 1.0000x reference)
//
#include <hip/hip_runtime.h>
#include <cmath>

#define RMAXF 5.0f
#define INV_AVG (1.0f/16.0f)
#define SQ4PI 3.5449077018110318f

// Real sph harmonics l=0..3 (times sqrt(4pi)) of unit vector (x,y,z)
__device__ __forceinline__ void sph16(float x, float y, float z, float* Y){
  float x2=x*x, y2=y*y, z2=z*z;
  Y[0]=SQ4PI*0.28209479177387814f;
  Y[1]=SQ4PI*0.4886025119029199f*y;
  Y[2]=SQ4PI*0.4886025119029199f*z;
  Y[3]=SQ4PI*0.4886025119029199f*x;
  Y[4]=SQ4PI*1.0925484305920792f*x*y;
  Y[5]=SQ4PI*1.0925484305920792f*y*z;
  Y[6]=SQ4PI*0.31539156525252005f*(3.f*z2-1.f);
  Y[7]=SQ4PI*1.0925484305920792f*x*z;
  Y[8]=SQ4PI*0.5462742152960396f*(x2-y2);
  Y[9]=SQ4PI*0.5900435899266435f*y*(3.f*x2-y2);
  Y[10]=SQ4PI*2.890611442640554f*x*y*z;
  Y[11]=SQ4PI*0.4570457994644658f*y*(5.f*z2-1.f);
  Y[12]=SQ4PI*0.3731763325901154f*z*(5.f*z2-3.f);
  Y[13]=SQ4PI*0.4570457994644658f*x*(5.f*z2-1.f);
  Y[14]=SQ4PI*1.445305721320277f*z*(x2-y2);
  Y[15]=SQ4PI*0.5900435899266435f*x*(x2-3.f*y2);
}

// radial basis ef[8] = bess*fcut and d(ef)/dr. Caller guarantees r < RMAX.
__device__ __forceinline__ void radial(float r, bool want_d, float* ef, float* def){
  const float PI_ = 3.14159265358979323846f;
  const float c = 0.6324555320336759f; // sqrt(2/5)
  float xr = r*(1.0f/RMAXF);
  float x2=xr*xr, x3=x2*xr, x5=x3*x2, x6=x5*xr, x7=x6*xr, x8=x7*xr;
  float fcut = 1.f - 28.f*x6 + 48.f*x7 - 21.f*x8;
  float om = 1.f - xr;
  float dfcut = -168.f*x5*om*om*(1.0f/RMAXF);
  float invr = 1.f/r;
  #pragma unroll
  for(int n=1;n<=8;n++){
    float a = (float)n*PI_*(1.0f/RMAXF);
    float ar = a*r;
    float s = sinf(ar), co = cosf(ar);
    float b = c*s*invr;
    ef[n-1] = b*fcut;
    if(want_d) def[n-1] = c*(a*co - s*invr)*invr*fcut + b*dfcut;
  }
}

// ---------------- node embed: h = attrs @ W_embed, e0 atomic per graph ----
__global__ __launch_bounds__(64) void embed_k(
    const float* __restrict__ attrs, const float* __restrict__ W_embed,
    const float* __restrict__ ae, const int* __restrict__ batch,
    float* __restrict__ h, float* __restrict__ e_acc, int N)
{
  int n = blockIdx.x;
  if(n >= N) return;
  int k = threadIdx.x;
  float acc = 0.f;
  #pragma unroll
  for(int s=0;s<10;s++) acc += attrs[n*10+s]*W_embed[s*64+k];
  h[(size_t)n*64+k] = acc;
  if(k==0){
    float e0 = 0.f;
    #pragma unroll
    for(int s=0;s<10;s++) e0 += attrs[n*10+s]*ae[s];
    atomicAdd(&e_acc[batch[n]*2+0], e0);
  }
}

// ---------------- transpose W_r2 -> W2T[k][j] = W_r2[j][k] ----------------
__global__ void tr_k(const float* __restrict__ W_r2, float* __restrict__ W2T){
  int i = threadIdx.x + blockIdx.x*blockDim.x;
  if(i < 4096){ int j = i>>6, k = i&63; W2T[k*64+j] = W_r2[i]; }
}

// ---------------- CSR build over surviving edges (r < RMAX), key = recv ---
__global__ __launch_bounds__(256) void count_k(
    const float* __restrict__ pos, const float* __restrict__ shifts,
    const int* __restrict__ eidx, int* __restrict__ deg, int E)
{
  int e = blockIdx.x*256 + threadIdx.x;
  if(e >= E) return;
  int snd = eidx[e], rcv = eidx[E+e];
  float vx = pos[rcv*3+0]-pos[snd*3+0]+shifts[e*3+0];
  float vy = pos[rcv*3+1]-pos[snd*3+1]+shifts[e*3+1];
  float vz = pos[rcv*3+2]-pos[snd*3+2]+shifts[e*3+2];
  float r2 = vx*vx+vy*vy+vz*vz + 1e-12f;
  if(r2 < RMAXF*RMAXF) atomicAdd(&deg[rcv], 1);
}

__global__ __launch_bounds__(256) void scan_k(
    const int* __restrict__ deg, int* __restrict__ rowptr,
    int* __restrict__ cursor, int N)
{
  __shared__ int part[256];
  int tid = threadIdx.x;
  int chunk = (N + 255) / 256;
  int begin = tid*chunk, end = begin+chunk < N ? begin+chunk : N;
  int s = 0;
  for(int i=begin;i<end;i++) s += deg[i];
  part[tid] = s;
  __syncthreads();
  for(int off=1; off<256; off<<=1){
    int t = (tid >= off) ? part[tid-off] : 0;
    __syncthreads();
    part[tid] += t;
    __syncthreads();
  }
  int run = part[tid] - s;   // exclusive prefix of this thread's chunk
  for(int i=begin;i<end;i++){
    rowptr[i] = run; cursor[i] = run; run += deg[i];
  }
  if(tid == 255) rowptr[N] = part[255];
}

__global__ __launch_bounds__(256) void scatter_k(
    const float* __restrict__ pos, const float* __restrict__ shifts,
    const int* __restrict__ eidx, int* __restrict__ cursor,
    int* __restrict__ elist, int E)
{
  int e = blockIdx.x*256 + threadIdx.x;
  if(e >= E) return;
  int snd = eidx[e], rcv = eidx[E+e];
  float vx = pos[rcv*3+0]-pos[snd*3+0]+shifts[e*3+0];
  float vy = pos[rcv*3+1]-pos[snd*3+1]+shifts[e*3+1];
  float vz = pos[rcv*3+2]-pos[snd*3+2]+shifts[e*3+2];
  float r2 = vx*vx+vy*vy+vz*vz + 1e-12f;
  if(r2 < RMAXF*RMAXF){
    int p = atomicAdd(&cursor[rcv], 1);
    elist[p] = e;
  }
}

// ---------------- edge forward (gather): A[n][lm][k] in registers ---------
__global__ __launch_bounds__(256) void edge_fwd_g(
    const float* __restrict__ pos, const float* __restrict__ shifts,
    const int* __restrict__ eidx, const float* __restrict__ h,
    const float* __restrict__ W_r1, const float* __restrict__ W_r2,
    const int* __restrict__ rowptr, const int* __restrict__ elist,
    float* __restrict__ A, int N, int E)
{
  __shared__ float sW1[512];
  __shared__ float sW2[4096];
  __shared__ float s_silu[4][64];
  int tid = threadIdx.x;
  for(int i=tid;i<512;i+=256)  sW1[i] = W_r1[i];
  for(int i=tid;i<4096;i+=256) sW2[i] = W_r2[i];
  __syncthreads();
  int ws = tid >> 6, lane = tid & 63;
  int n = blockIdx.x*4 + ws;
  if(n >= N) return;
  int beg = rowptr[n], endp = rowptr[n+1];
  float acc[16];
  #pragma unroll
  for(int lm=0;lm<16;lm++) acc[lm] = 0.f;
  float px = pos[n*3+0], py = pos[n*3+1], pz = pos[n*3+2];
  for(int idx=beg; idx<endp; idx++){
    int e = elist[idx];
    int snd = eidx[e];
    float vx = px - pos[snd*3+0] + shifts[e*3+0];
    float vy = py - pos[snd*3+1] + shifts[e*3+1];
    float vz = pz - pos[snd*3+2] + shifts[e*3+2];
    float r = sqrtf(vx*vx+vy*vy+vz*vz + 1e-12f);
    float invr = 1.f/r;
    float ux=vx*invr, uy=vy*invr, uz=vz*invr;
    float Y[16]; sph16(ux,uy,uz,Y);
    float ef[8]; radial(r,false,ef,nullptr);
    float t = 0.f;
    #pragma unroll
    for(int j=0;j<8;j++) t += ef[j]*sW1[j*64+lane];
    float sig = 1.f/(1.f+expf(-t));
    s_silu[ws][lane] = t*sig;
    float w = 0.f;
    for(int j=0;j<64;j++) w += s_silu[ws][j]*sW2[j*64+lane];
    float wh = w * h[(size_t)snd*64+lane] * INV_AVG;
    #pragma unroll
    for(int lm=0;lm<16;lm++) acc[lm] += wh*Y[lm];
  }
  float* Ab = A + (size_t)n*1024 + lane;
  #pragma unroll
  for(int lm=0;lm<16;lm++) Ab[lm*64] = acc[lm];
}

// ---------------- node: Am, s, B, node_e, and gA (in-place over A) --------
__global__ __launch_bounds__(256) void node_k(
    float* __restrict__ A,              // [N][16][64], overwritten with gA
    const float* __restrict__ W_mix,    // [4][64][64]
    const float* __restrict__ W_prod,   // [3][64]
    const float* __restrict__ w_ro,     // [64]
    const int* __restrict__ batch, float* __restrict__ e_acc, int N)
{
  __shared__ float sW[16384];
  __shared__ float sA[1024];
  __shared__ float sG[1024];
  __shared__ float sS[4][64];
  __shared__ float sSf[64];
  __shared__ float sA0[64];

  const int tid = threadIdx.x;
  const int c = tid & 63;
  const int lmg = tid >> 6;
  const int swz = (c & 7) << 2;

  for(int i = tid; i < 16384; i += 256){
    int l = i >> 12, k = (i >> 6) & 63, cc = i & 63;
    sW[l*4096 + cc*64 + (k ^ ((cc&7)<<2))] = W_mix[i];
  }

  const float wp0 = W_prod[c], wp1 = W_prod[64+c], wp2 = W_prod[128+c], wr = w_ro[c];
  const int lA = (lmg==0)?0:((lmg<3)?2:3);
  const int lB = (lmg==0)?1:((lmg==1)?2:3);
  const float* wBa = &sW[lA*4096 + c*64];
  const float* wBb = &sW[lB*4096 + c*64];
  const float* aB0 = &sA[(lmg*4+0)*64];
  const float* aB1 = &sA[(lmg*4+1)*64];
  const float* aB2 = &sA[(lmg*4+2)*64];
  const float* aB3 = &sA[(lmg*4+3)*64];
  float* gB0 = &sG[(lmg*4+0)*64];
  float* gB1 = &sG[(lmg*4+1)*64];
  float* gB2 = &sG[(lmg*4+2)*64];
  float* gB3 = &sG[(lmg*4+3)*64];

  for(int n = blockIdx.x; n < N; n += gridDim.x){
    reinterpret_cast<float4*>(sA)[tid] =
        reinterpret_cast<const float4*>(A + (size_t)n*1024)[tid];
    __syncthreads();

    float am0=0.f, am1=0.f, am2=0.f, am3=0.f;
    #pragma unroll
    for(int kb=0; kb<16; kb++){
      int ko = (kb*4) ^ swz;
      float4 wa = *reinterpret_cast<const float4*>(wBa + ko);
      float4 wb = *reinterpret_cast<const float4*>(wBb + ko);
      float4 a0 = *reinterpret_cast<const float4*>(aB0 + kb*4);
      float4 a1 = *reinterpret_cast<const float4*>(aB1 + kb*4);
      float4 a2 = *reinterpret_cast<const float4*>(aB2 + kb*4);
      float4 a3 = *reinterpret_cast<const float4*>(aB3 + kb*4);
      am0 += a0.x*wa.x + a0.y*wa.y + a0.z*wa.z + a0.w*wa.w;
      am1 += a1.x*wb.x + a1.y*wb.y + a1.z*wb.z + a1.w*wb.w;
      am2 += a2.x*wb.x + a2.y*wb.y + a2.z*wb.z + a2.w*wb.w;
      am3 += a3.x*wb.x + a3.y*wb.y + a3.z*wb.z + a3.w*wb.w;
    }
    float part = am0*am0 + am1*am1 + am2*am2 + am3*am3;
    sS[lmg][c] = part;
    __syncthreads();
    if(lmg==0){
      sSf[c] = sS[0][c]+sS[1][c]+sS[2][c]+sS[3][c];
      sA0[c] = am0;
    }
    __syncthreads();
    float s_ = sSf[c], a0_ = sA0[c];
    if(lmg==0){
      float B = wp0*a0_ + wp1*s_ + wp2*a0_*s_;
      float v = B*wr;
      #pragma unroll
      for(int off=32; off; off>>=1) v += __shfl_xor(v, off, 64);
      if(c==0) atomicAdd(&e_acc[batch[n]*2+1], v);
    }
    float gs = wr*(wp1 + wp2*a0_);
    {
      float g0 = gs*2.f*am0;
      if(lmg==0) g0 += wr*(wp0 + wp2*s_);
      gB0[c] = g0;
      gB1[c] = gs*2.f*am1;
      gB2[c] = gs*2.f*am2;
      gB3[c] = gs*2.f*am3;
    }
    __syncthreads();

    float ga0=0.f, ga1=0.f, ga2=0.f, ga3=0.f;
    #pragma unroll
    for(int cb=0; cb<16; cb++){
      float g0[4], g1[4], g2[4], g3[4];
      *reinterpret_cast<float4*>(g0) = *reinterpret_cast<const float4*>(gB0 + cb*4);
      *reinterpret_cast<float4*>(g1) = *reinterpret_cast<const float4*>(gB1 + cb*4);
      *reinterpret_cast<float4*>(g2) = *reinterpret_cast<const float4*>(gB2 + cb*4);
      *reinterpret_cast<float4*>(g3) = *reinterpret_cast<const float4*>(gB3 + cb*4);
      #pragma unroll
      for(int j=0;j<4;j++){
        int cc = cb*4 + j;
        int sidx = cc*64 + (c ^ ((cc&7)<<2));
        float wa = sW[lA*4096 + sidx];
        float wb = sW[lB*4096 + sidx];
        ga0 += wa*g0[j];
        ga1 += wb*g1[j];
        ga2 += wb*g2[j];
        ga3 += wb*g3[j];
      }
    }
    float* dst = A + (size_t)n*1024 + (size_t)lmg*256 + c;
    dst[0]   = ga0;
    dst[64]  = ga1;
    dst[128] = ga2;
    dst[192] = ga3;
    __syncthreads();
  }
}

// ---------------- edge backward (gather): forces --------------------------
__global__ __launch_bounds__(256) void edge_bwd_g(
    const float* __restrict__ pos, const float* __restrict__ shifts,
    const int* __restrict__ eidx, const float* __restrict__ h,
    const float* __restrict__ W_r1, const float* __restrict__ W_r2,
    const float* __restrict__ W2T, const float* __restrict__ gA,
    const int* __restrict__ rowptr, const int* __restrict__ elist,
    float* __restrict__ forces, int N, int E)
{
  __shared__ float sW1[512];
  __shared__ float sW2[4096];
  __shared__ float sWT[4096];
  __shared__ float s_silu[4][64];
  __shared__ float s_gw[4][64];
  int tid = threadIdx.x;
  for(int i=tid;i<512;i+=256)  sW1[i] = W_r1[i];
  for(int i=tid;i<4096;i+=256){ sW2[i] = W_r2[i]; sWT[i] = W2T[i]; }
  __syncthreads();
  int ws = tid >> 6, lane = tid & 63;
  int n = blockIdx.x*4 + ws;
  if(n >= N) return;
  int beg = rowptr[n], endp = rowptr[n+1];
  if(beg == endp) return;
  float gm[16];
  {
    const float* gb = gA + (size_t)n*1024 + lane;
    #pragma unroll
    for(int lm=0;lm<16;lm++) gm[lm] = gb[lm*64]*INV_AVG;
  }
  float px = pos[n*3+0], py = pos[n*3+1], pz = pos[n*3+2];
  float fx=0.f, fy=0.f, fz=0.f;
  const float c1=0.4886025119029199f, c2=1.0925484305920792f, c3=0.31539156525252005f;
  const float c4=0.5462742152960396f, c5=0.5900435899266435f, c6=2.890611442640554f;
  const float c7=0.4570457994644658f, c8=0.3731763325901154f, c9=1.445305721320277f;

  for(int idx=beg; idx<endp; idx++){
    int e = elist[idx];
    int snd = eidx[e];
    float vx = px - pos[snd*3+0] + shifts[e*3+0];
    float vy = py - pos[snd*3+1] + shifts[e*3+1];
    float vz = pz - pos[snd*3+2] + shifts[e*3+2];
    float r = sqrtf(vx*vx+vy*vy+vz*vz + 1e-12f);
    float invr = 1.f/r;
    float x=vx*invr, y=vy*invr, z=vz*invr;
    float Y[16]; sph16(x,y,z,Y);
    float ef[8], def[8]; radial(r,true,ef,def);
    float t = 0.f;
    #pragma unroll
    for(int j=0;j<8;j++) t += ef[j]*sW1[j*64+lane];
    float sig = 1.f/(1.f+expf(-t));
    s_silu[ws][lane] = t*sig;
    float w = 0.f;
    for(int j=0;j<64;j++) w += s_silu[ws][j]*sW2[j*64+lane];
    float hk = h[(size_t)snd*64+lane];
    float wh = w*hk;
    // gw[k] = hk * sum_lm gm*Y
    float gw = 0.f;
    #pragma unroll
    for(int lm=0;lm<16;lm++) gw += gm[lm]*Y[lm];
    gw *= hk;
    // dY/du contracted with gm per lane, then one butterfly per component
    float x2=x*x, y2=y*y, z2=z*z;
    float fz1 = 5.f*z2-1.f;
    float gxp = c1*gm[3] + c2*(y*gm[4] + z*gm[7]) + 2.f*c4*x*gm[8]
              + 6.f*c5*x*y*gm[9] + c6*y*z*gm[10] + c7*fz1*gm[13]
              + 2.f*c9*x*z*gm[14] + 3.f*c5*(x2-y2)*gm[15];
    float gyp = c1*gm[1] + c2*(x*gm[4] + z*gm[5]) - 2.f*c4*y*gm[8]
              + 3.f*c5*(x2-y2)*gm[9] + c6*x*z*gm[10] + c7*fz1*gm[11]
              - 2.f*c9*y*z*gm[14] - 6.f*c5*x*y*gm[15];
    float gzp = c1*gm[2] + c2*(y*gm[5] + x*gm[7]) + 6.f*c3*z*gm[6]
              + c6*x*y*gm[10] + 10.f*c7*y*z*gm[11] + c8*(15.f*z2-3.f)*gm[12]
              + 10.f*c7*x*z*gm[13] + c9*(x2-y2)*gm[14];
    float gx = gxp*wh*SQ4PI, gy = gyp*wh*SQ4PI, gz = gzp*wh*SQ4PI;
    // g_silu -> gt
    s_gw[ws][lane] = gw;
    float gsil = 0.f;
    for(int k=0;k<64;k++) gsil += s_gw[ws][k]*sWT[k*64+lane];
    float gt = gsil * sig*(1.f + t*(1.f-sig));
    // gr partial: rk = sum_n W_r1[n][lane]*def[n]
    float rk = 0.f;
    #pragma unroll
    for(int j=0;j<8;j++) rk += sW1[j*64+lane]*def[j];
    float grp = gt*rk;
    // butterfly-sum 4 scalars across the wave
    #pragma unroll
    for(int off=32; off; off>>=1){
      gx  += __shfl_xor(gx,  off, 64);
      gy  += __shfl_xor(gy,  off, 64);
      gz  += __shfl_xor(gz,  off, 64);
      grp += __shfl_xor(grp, off, 64);
    }
    float udot = x*gx + y*gy + z*gz;
    float gvx = grp*x + (gx - udot*x)*invr;
    float gvy = grp*y + (gy - udot*y)*invr;
    float gvz = grp*z + (gz - udot*z)*invr;
    fx -= gvx; fy -= gvy; fz -= gvz;
    if(lane==0){
      atomicAdd(&forces[snd*3+0],  gvx);
      atomicAdd(&forces[snd*3+1],  gvy);
      atomicAdd(&forces[snd*3+2],  gvz);
    }
  }
  if(lane==0){
    atomicAdd(&forces[n*3+0], fx);
    atomicAdd(&forces[n*3+1], fy);
    atomicAdd(&forces[n*3+2], fz);
  }
}

// ---------------- finalize ---------------------------------------------
__global__ void fin_k(const float* __restrict__ e_acc, float* __restrict__ out, int G){
  int g = threadIdx.x;
  if(g < G){
    float e0 = e_acc[2*g], e1 = e_acc[2*g+1];
    out[g] = e0+e1;
    out[G + 2*g] = e0;
    out[G + 2*g+1] = e1;
  }
}

extern "C" void kernel_launch(void* const* d_in, const int* in_sizes, int n_in,
                              void* d_out, int out_size, void* d_ws, size_t ws_size,
                              hipStream_t stream) {
  const float* positions  = (const float*)d_in[0];
  const float* node_attrs = (const float*)d_in[1];
  const float* shifts     = (const float*)d_in[2];
  const float* W_embed    = (const float*)d_in[3];
  const float* at_en      = (const float*)d_in[4];
  const float* W_r1       = (const float*)d_in[5];
  const float* W_r2       = (const float*)d_in[6];
  const float* W_mix      = (const float*)d_in[7];
  const float* W_prod     = (const float*)d_in[8];
  const float* w_ro       = (const float*)d_in[9];
  const int*   edge_index = (const int*)d_in[10];
  const int*   batch      = (const int*)d_in[11];

  int N = in_sizes[0]/3;
  int E = in_sizes[10]/2;
  int G = (out_size - 3*N)/3;

  float* out    = (float*)d_out;
  float* A      = (float*)d_ws;                 // N*1024
  float* h      = A + (size_t)N*1024;           // N*64
  float* W2T    = h + (size_t)N*64;             // 4096
  float* eacc   = W2T + 4096;                   // 2G
  int*   deg    = (int*)(eacc + 2*G);           // N
  int*   rowptr = deg + N;                      // N+1
  int*   cursor = rowptr + N + 1;               // N
  int*   elist  = cursor + N;                   // E

  hipMemsetAsync(d_out, 0, (size_t)out_size*sizeof(float), stream);
  hipMemsetAsync(eacc, 0, (size_t)2*G*sizeof(float), stream);
  hipMemsetAsync(deg, 0, (size_t)N*sizeof(int), stream);

  embed_k<<<N, 64, 0, stream>>>(node_attrs, W_embed, at_en, batch, h, eacc, N);
  tr_k<<<16, 256, 0, stream>>>(W_r2, W2T);
  count_k<<<(E+255)/256, 256, 0, stream>>>(positions, shifts, edge_index, deg, E);
  scan_k<<<1, 256, 0, stream>>>(deg, rowptr, cursor, N);
  scatter_k<<<(E+255)/256, 256, 0, stream>>>(positions, shifts, edge_index, cursor, elist, E);
  edge_fwd_g<<<(N+3)/4, 256, 0, stream>>>(positions, shifts, edge_index, h, W_r1, W_r2, rowptr, elist, A, N, E);
  node_k<<<512, 256, 0, stream>>>(A, W_mix, W_prod, w_ro, batch, eacc, N);
  edge_bwd_g<<<(N+3)/4, 256, 0, stream>>>(positions, shifts, edge_index, h, W_r1, W_r2, W2T, A, rowptr, elist, out + 3*G, N, E);
  fin_k<<<1, 64, 0, stream>>>(eacc, out, G);
}

// Round 4
// 523.190 us; speedup vs baseline: 1.3635x; 1.3635x over previous
//
#include <hip/hip_runtime.h>
#include <cmath>

#define RMAXF 5.0f
#define INV_AVG (1.0f/16.0f)
#define SQ4PI 3.5449077018110318f

// Real sph harmonics l=0..3 (times sqrt(4pi)) of unit vector (x,y,z)
__device__ __forceinline__ void sph16(float x, float y, float z, float* Y){
  float x2=x*x, y2=y*y, z2=z*z;
  Y[0]=SQ4PI*0.28209479177387814f;
  Y[1]=SQ4PI*0.4886025119029199f*y;
  Y[2]=SQ4PI*0.4886025119029199f*z;
  Y[3]=SQ4PI*0.4886025119029199f*x;
  Y[4]=SQ4PI*1.0925484305920792f*x*y;
  Y[5]=SQ4PI*1.0925484305920792f*y*z;
  Y[6]=SQ4PI*0.31539156525252005f*(3.f*z2-1.f);
  Y[7]=SQ4PI*1.0925484305920792f*x*z;
  Y[8]=SQ4PI*0.5462742152960396f*(x2-y2);
  Y[9]=SQ4PI*0.5900435899266435f*y*(3.f*x2-y2);
  Y[10]=SQ4PI*2.890611442640554f*x*y*z;
  Y[11]=SQ4PI*0.4570457994644658f*y*(5.f*z2-1.f);
  Y[12]=SQ4PI*0.3731763325901154f*z*(5.f*z2-3.f);
  Y[13]=SQ4PI*0.4570457994644658f*x*(5.f*z2-1.f);
  Y[14]=SQ4PI*1.445305721320277f*z*(x2-y2);
  Y[15]=SQ4PI*0.5900435899266435f*x*(x2-3.f*y2);
}

// radial basis ef[8] = bess*fcut and d(ef)/dr. Caller guarantees r < RMAX.
__device__ __forceinline__ void radial(float r, bool want_d, float* ef, float* def){
  const float PI_ = 3.14159265358979323846f;
  const float c = 0.6324555320336759f; // sqrt(2/5)
  float xr = r*(1.0f/RMAXF);
  float x2=xr*xr, x3=x2*xr, x5=x3*x2, x6=x5*xr, x7=x6*xr, x8=x7*xr;
  float fcut = 1.f - 28.f*x6 + 48.f*x7 - 21.f*x8;
  float om = 1.f - xr;
  float dfcut = -168.f*x5*om*om*(1.0f/RMAXF);
  float invr = 1.f/r;
  #pragma unroll
  for(int n=1;n<=8;n++){
    float a = (float)n*PI_*(1.0f/RMAXF);
    float ar = a*r;
    float s, co;
    if(want_d){ sincosf(ar, &s, &co); } else { s = sinf(ar); co = 0.f; }
    float b = c*s*invr;
    ef[n-1] = b*fcut;
    if(want_d) def[n-1] = c*(a*co - s*invr)*invr*fcut + b*dfcut;
  }
}

// ---------------- node embed: h = attrs @ W_embed, e0 atomic per graph ----
__global__ __launch_bounds__(64) void embed_k(
    const float* __restrict__ attrs, const float* __restrict__ W_embed,
    const float* __restrict__ ae, const int* __restrict__ batch,
    float* __restrict__ h, float* __restrict__ e_acc, int N)
{
  int n = blockIdx.x;
  if(n >= N) return;
  int k = threadIdx.x;
  float acc = 0.f;
  #pragma unroll
  for(int s=0;s<10;s++) acc += attrs[n*10+s]*W_embed[s*64+k];
  h[(size_t)n*64+k] = acc;
  if(k==0){
    float e0 = 0.f;
    #pragma unroll
    for(int s=0;s<10;s++) e0 += attrs[n*10+s]*ae[s];
    atomicAdd(&e_acc[batch[n]*2+0], e0);
  }
}

// ---------------- transpose W_r2 -> W2T[k][j] = W_r2[j][k] ----------------
__global__ void tr_k(const float* __restrict__ W_r2, float* __restrict__ W2T){
  int i = threadIdx.x + blockIdx.x*blockDim.x;
  if(i < 4096){ int j = i>>6, k = i&63; W2T[k*64+j] = W_r2[i]; }
}

// ---------------- CSR build over surviving edges (r < RMAX), key = recv ---
__global__ __launch_bounds__(256) void count_k(
    const float* __restrict__ pos, const float* __restrict__ shifts,
    const int* __restrict__ eidx, int* __restrict__ deg, int E)
{
  int e = blockIdx.x*256 + threadIdx.x;
  if(e >= E) return;
  int snd = eidx[e], rcv = eidx[E+e];
  float vx = pos[rcv*3+0]-pos[snd*3+0]+shifts[e*3+0];
  float vy = pos[rcv*3+1]-pos[snd*3+1]+shifts[e*3+1];
  float vz = pos[rcv*3+2]-pos[snd*3+2]+shifts[e*3+2];
  float r2 = vx*vx+vy*vy+vz*vz + 1e-12f;
  if(r2 < RMAXF*RMAXF) atomicAdd(&deg[rcv], 1);
}

__global__ __launch_bounds__(256) void scan_k(
    const int* __restrict__ deg, int* __restrict__ rowptr,
    int* __restrict__ cursor, int N)
{
  __shared__ int part[256];
  int tid = threadIdx.x;
  int chunk = (N + 255) / 256;
  int begin = tid*chunk, end = begin+chunk < N ? begin+chunk : N;
  int s = 0;
  for(int i=begin;i<end;i++) s += deg[i];
  part[tid] = s;
  __syncthreads();
  for(int off=1; off<256; off<<=1){
    int t = (tid >= off) ? part[tid-off] : 0;
    __syncthreads();
    part[tid] += t;
    __syncthreads();
  }
  int run = part[tid] - s;   // exclusive prefix of this thread's chunk
  for(int i=begin;i<end;i++){
    rowptr[i] = run; cursor[i] = run; run += deg[i];
  }
  if(tid == 255) rowptr[N] = part[255];
}

__global__ __launch_bounds__(256) void scatter_k(
    const float* __restrict__ pos, const float* __restrict__ shifts,
    const int* __restrict__ eidx, int* __restrict__ cursor,
    int* __restrict__ elist, int E)
{
  int e = blockIdx.x*256 + threadIdx.x;
  if(e >= E) return;
  int snd = eidx[e], rcv = eidx[E+e];
  float vx = pos[rcv*3+0]-pos[snd*3+0]+shifts[e*3+0];
  float vy = pos[rcv*3+1]-pos[snd*3+1]+shifts[e*3+1];
  float vz = pos[rcv*3+2]-pos[snd*3+2]+shifts[e*3+2];
  float r2 = vx*vx+vy*vy+vz*vz + 1e-12f;
  if(r2 < RMAXF*RMAXF){
    int p = atomicAdd(&cursor[rcv], 1);
    elist[p] = e;
  }
}

// ---------------- edge forward: one block per node, 4 waves on its edges --
__global__ __launch_bounds__(256) void fwd_fused(
    const float* __restrict__ pos, const float* __restrict__ shifts,
    const int* __restrict__ eidx, const float* __restrict__ h,
    const float* __restrict__ W_r1, const float* __restrict__ W_r2,
    const int* __restrict__ rowptr, const int* __restrict__ elist,
    float* __restrict__ A, int N, int E)
{
  __shared__ float sW1[512];
  __shared__ float sW2[4096];
  __shared__ float accT[1024];
  __shared__ float s_sil[4][64];
  int tid = threadIdx.x, ws = tid >> 6, lane = tid & 63;
  for(int i=tid;i<512;i+=256)  sW1[i] = W_r1[i];
  for(int i=tid;i<4096;i+=256) sW2[i] = W_r2[i];

  for(int n = blockIdx.x; n < N; n += gridDim.x){
    float acc[16];
    #pragma unroll
    for(int lm=0;lm<16;lm++) acc[lm] = 0.f;
    for(int i=tid;i<1024;i+=256) accT[i] = 0.f;
    __syncthreads();   // staging + accT zero visible

    int beg = rowptr[n], endp = rowptr[n+1];
    float px = pos[n*3+0], py = pos[n*3+1], pz = pos[n*3+2];
    for(int idx = beg + ws; idx < endp; idx += 4){
      int e = elist[idx];
      int snd = eidx[e];
      float vx = px - pos[snd*3+0] + shifts[e*3+0];
      float vy = py - pos[snd*3+1] + shifts[e*3+1];
      float vz = pz - pos[snd*3+2] + shifts[e*3+2];
      float r = sqrtf(vx*vx+vy*vy+vz*vz + 1e-12f);
      float invr = 1.f/r;
      float ux=vx*invr, uy=vy*invr, uz=vz*invr;
      float Y[16]; sph16(ux,uy,uz,Y);
      float ef[8]; radial(r,false,ef,nullptr);
      float t = 0.f;
      #pragma unroll
      for(int j=0;j<8;j++) t += ef[j]*sW1[j*64+lane];
      float sig = 1.f/(1.f+expf(-t));
      s_sil[ws][lane] = t*sig;       // wave-local slice, no barrier needed
      float w = 0.f;
      for(int j=0;j<64;j++) w += s_sil[ws][j]*sW2[j*64+lane];
      float wh = w * h[(size_t)snd*64+lane] * INV_AVG;
      #pragma unroll
      for(int lm=0;lm<16;lm++) acc[lm] += wh*Y[lm];
    }
    // combine 4 waves
    #pragma unroll
    for(int w4=0;w4<4;w4++){
      if(ws==w4){
        #pragma unroll
        for(int lm=0;lm<16;lm++) accT[lm*64+lane] += acc[lm];
      }
      __syncthreads();
    }
    reinterpret_cast<float4*>(A + (size_t)n*1024)[tid] =
        reinterpret_cast<const float4*>(accT)[tid];
    __syncthreads();   // all stores done before accT re-zeroed next iter
  }
}

// ---------------- node: Am, s, B, node_e, and gA (in-place over A) --------
__global__ __launch_bounds__(256) void node_k(
    float* __restrict__ A,              // [N][16][64], overwritten with gA
    const float* __restrict__ W_mix,    // [4][64][64]
    const float* __restrict__ W_prod,   // [3][64]
    const float* __restrict__ w_ro,     // [64]
    const int* __restrict__ batch, float* __restrict__ e_acc, int N)
{
  __shared__ float sW[16384];
  __shared__ float sA[1024];
  __shared__ float sG[1024];
  __shared__ float sS[4][64];
  __shared__ float sSf[64];
  __shared__ float sA0[64];

  const int tid = threadIdx.x;
  const int c = tid & 63;
  const int lmg = tid >> 6;
  const int swz = (c & 7) << 2;

  for(int i = tid; i < 16384; i += 256){
    int l = i >> 12, k = (i >> 6) & 63, cc = i & 63;
    sW[l*4096 + cc*64 + (k ^ ((cc&7)<<2))] = W_mix[i];
  }

  const float wp0 = W_prod[c], wp1 = W_prod[64+c], wp2 = W_prod[128+c], wr = w_ro[c];
  const int lA = (lmg==0)?0:((lmg<3)?2:3);
  const int lB = (lmg==0)?1:((lmg==1)?2:3);
  const float* wBa = &sW[lA*4096 + c*64];
  const float* wBb = &sW[lB*4096 + c*64];
  const float* aB0 = &sA[(lmg*4+0)*64];
  const float* aB1 = &sA[(lmg*4+1)*64];
  const float* aB2 = &sA[(lmg*4+2)*64];
  const float* aB3 = &sA[(lmg*4+3)*64];
  float* gB0 = &sG[(lmg*4+0)*64];
  float* gB1 = &sG[(lmg*4+1)*64];
  float* gB2 = &sG[(lmg*4+2)*64];
  float* gB3 = &sG[(lmg*4+3)*64];

  for(int n = blockIdx.x; n < N; n += gridDim.x){
    reinterpret_cast<float4*>(sA)[tid] =
        reinterpret_cast<const float4*>(A + (size_t)n*1024)[tid];
    __syncthreads();

    float am0=0.f, am1=0.f, am2=0.f, am3=0.f;
    #pragma unroll
    for(int kb=0; kb<16; kb++){
      int ko = (kb*4) ^ swz;
      float4 wa = *reinterpret_cast<const float4*>(wBa + ko);
      float4 wb = *reinterpret_cast<const float4*>(wBb + ko);
      float4 a0 = *reinterpret_cast<const float4*>(aB0 + kb*4);
      float4 a1 = *reinterpret_cast<const float4*>(aB1 + kb*4);
      float4 a2 = *reinterpret_cast<const float4*>(aB2 + kb*4);
      float4 a3 = *reinterpret_cast<const float4*>(aB3 + kb*4);
      am0 += a0.x*wa.x + a0.y*wa.y + a0.z*wa.z + a0.w*wa.w;
      am1 += a1.x*wb.x + a1.y*wb.y + a1.z*wb.z + a1.w*wb.w;
      am2 += a2.x*wb.x + a2.y*wb.y + a2.z*wb.z + a2.w*wb.w;
      am3 += a3.x*wb.x + a3.y*wb.y + a3.z*wb.z + a3.w*wb.w;
    }
    float part = am0*am0 + am1*am1 + am2*am2 + am3*am3;
    sS[lmg][c] = part;
    __syncthreads();
    if(lmg==0){
      sSf[c] = sS[0][c]+sS[1][c]+sS[2][c]+sS[3][c];
      sA0[c] = am0;
    }
    __syncthreads();
    float s_ = sSf[c], a0_ = sA0[c];
    if(lmg==0){
      float B = wp0*a0_ + wp1*s_ + wp2*a0_*s_;
      float v = B*wr;
      #pragma unroll
      for(int off=32; off; off>>=1) v += __shfl_xor(v, off, 64);
      if(c==0) atomicAdd(&e_acc[batch[n]*2+1], v);
    }
    float gs = wr*(wp1 + wp2*a0_);
    {
      float g0 = gs*2.f*am0;
      if(lmg==0) g0 += wr*(wp0 + wp2*s_);
      gB0[c] = g0;
      gB1[c] = gs*2.f*am1;
      gB2[c] = gs*2.f*am2;
      gB3[c] = gs*2.f*am3;
    }
    __syncthreads();

    float ga0=0.f, ga1=0.f, ga2=0.f, ga3=0.f;
    #pragma unroll
    for(int cb=0; cb<16; cb++){
      float g0[4], g1[4], g2[4], g3[4];
      *reinterpret_cast<float4*>(g0) = *reinterpret_cast<const float4*>(gB0 + cb*4);
      *reinterpret_cast<float4*>(g1) = *reinterpret_cast<const float4*>(gB1 + cb*4);
      *reinterpret_cast<float4*>(g2) = *reinterpret_cast<const float4*>(gB2 + cb*4);
      *reinterpret_cast<float4*>(g3) = *reinterpret_cast<const float4*>(gB3 + cb*4);
      #pragma unroll
      for(int j=0;j<4;j++){
        int cc = cb*4 + j;
        int sidx = cc*64 + (c ^ ((cc&7)<<2));
        float wa = sW[lA*4096 + sidx];
        float wb = sW[lB*4096 + sidx];
        ga0 += wa*g0[j];
        ga1 += wb*g1[j];
        ga2 += wb*g2[j];
        ga3 += wb*g3[j];
      }
    }
    float* dst = A + (size_t)n*1024 + (size_t)lmg*256 + c;
    dst[0]   = ga0;
    dst[64]  = ga1;
    dst[128] = ga2;
    dst[192] = ga3;
    __syncthreads();
  }
}

// ---------------- edge backward: one block per node, 4 waves on its edges -
__global__ __launch_bounds__(256) void bwd_fused(
    const float* __restrict__ pos, const float* __restrict__ shifts,
    const int* __restrict__ eidx, const float* __restrict__ h,
    const float* __restrict__ W_r1, const float* __restrict__ W_r2,
    const float* __restrict__ W2T, const float* __restrict__ gA,
    const int* __restrict__ rowptr, const int* __restrict__ elist,
    float* __restrict__ forces, int N, int E)
{
  __shared__ float sW1[512];
  __shared__ float sW2[4096];
  __shared__ float sWT[4096];
  __shared__ float s_sil[4][64];
  __shared__ float s_gw[4][64];
  int tid = threadIdx.x, ws = tid >> 6, lane = tid & 63;
  for(int i=tid;i<512;i+=256)  sW1[i] = W_r1[i];
  for(int i=tid;i<4096;i+=256){ sW2[i] = W_r2[i]; sWT[i] = W2T[i]; }
  __syncthreads();   // sW* read-only afterwards; waves free-run from here

  const float c1=0.4886025119029199f, c2=1.0925484305920792f, c3=0.31539156525252005f;
  const float c4=0.5462742152960396f, c5=0.5900435899266435f, c6=2.890611442640554f;
  const float c7=0.4570457994644658f, c8=0.3731763325901154f, c9=1.445305721320277f;

  for(int n = blockIdx.x; n < N; n += gridDim.x){
    int beg = rowptr[n], endp = rowptr[n+1];
    if(beg == endp) continue;
    float gm[16];
    {
      const float* gb = gA + (size_t)n*1024 + lane;
      #pragma unroll
      for(int lm=0;lm<16;lm++) gm[lm] = gb[lm*64]*INV_AVG;
    }
    float px = pos[n*3+0], py = pos[n*3+1], pz = pos[n*3+2];
    float fx=0.f, fy=0.f, fz=0.f;

    for(int idx = beg + ws; idx < endp; idx += 4){
      int e = elist[idx];
      int snd = eidx[e];
      float vx = px - pos[snd*3+0] + shifts[e*3+0];
      float vy = py - pos[snd*3+1] + shifts[e*3+1];
      float vz = pz - pos[snd*3+2] + shifts[e*3+2];
      float r = sqrtf(vx*vx+vy*vy+vz*vz + 1e-12f);
      float invr = 1.f/r;
      float x=vx*invr, y=vy*invr, z=vz*invr;
      float Y[16]; sph16(x,y,z,Y);
      float ef[8], def[8]; radial(r,true,ef,def);
      float t = 0.f;
      #pragma unroll
      for(int j=0;j<8;j++) t += ef[j]*sW1[j*64+lane];
      float sig = 1.f/(1.f+expf(-t));
      s_sil[ws][lane] = t*sig;
      float w = 0.f;
      for(int j=0;j<64;j++) w += s_sil[ws][j]*sW2[j*64+lane];
      float hk = h[(size_t)snd*64+lane];
      float wh = w*hk;
      float gw = 0.f;
      #pragma unroll
      for(int lm=0;lm<16;lm++) gw += gm[lm]*Y[lm];
      gw *= hk;
      float x2=x*x, y2=y*y, z2=z*z;
      float fz1 = 5.f*z2-1.f;
      float gxp = c1*gm[3] + c2*(y*gm[4] + z*gm[7]) + 2.f*c4*x*gm[8]
                + 6.f*c5*x*y*gm[9] + c6*y*z*gm[10] + c7*fz1*gm[13]
                + 2.f*c9*x*z*gm[14] + 3.f*c5*(x2-y2)*gm[15];
      float gyp = c1*gm[1] + c2*(x*gm[4] + z*gm[5]) - 2.f*c4*y*gm[8]
                + 3.f*c5*(x2-y2)*gm[9] + c6*x*z*gm[10] + c7*fz1*gm[11]
                - 2.f*c9*y*z*gm[14] - 6.f*c5*x*y*gm[15];
      float gzp = c1*gm[2] + c2*(y*gm[5] + x*gm[7]) + 6.f*c3*z*gm[6]
                + c6*x*y*gm[10] + 10.f*c7*y*z*gm[11] + c8*(15.f*z2-3.f)*gm[12]
                + 10.f*c7*x*z*gm[13] + c9*(x2-y2)*gm[14];
      float gx = gxp*wh*SQ4PI, gy = gyp*wh*SQ4PI, gz = gzp*wh*SQ4PI;
      s_gw[ws][lane] = gw;
      float gsil = 0.f;
      for(int k=0;k<64;k++) gsil += s_gw[ws][k]*sWT[k*64+lane];
      float gt = gsil * sig*(1.f + t*(1.f-sig));
      float rk = 0.f;
      #pragma unroll
      for(int j=0;j<8;j++) rk += sW1[j*64+lane]*def[j];
      float grp = gt*rk;
      #pragma unroll
      for(int off=32; off; off>>=1){
        gx  += __shfl_xor(gx,  off, 64);
        gy  += __shfl_xor(gy,  off, 64);
        gz  += __shfl_xor(gz,  off, 64);
        grp += __shfl_xor(grp, off, 64);
      }
      float udot = x*gx + y*gy + z*gz;
      float gvx = grp*x + (gx - udot*x)*invr;
      float gvy = grp*y + (gy - udot*y)*invr;
      float gvz = grp*z + (gz - udot*z)*invr;
      fx -= gvx; fy -= gvy; fz -= gvz;
      if(lane==0){
        atomicAdd(&forces[snd*3+0],  gvx);
        atomicAdd(&forces[snd*3+1],  gvy);
        atomicAdd(&forces[snd*3+2],  gvz);
      }
    }
    if(lane==0){
      atomicAdd(&forces[n*3+0], fx);
      atomicAdd(&forces[n*3+1], fy);
      atomicAdd(&forces[n*3+2], fz);
    }
  }
}

// ---------------- finalize ---------------------------------------------
__global__ void fin_k(const float* __restrict__ e_acc, float* __restrict__ out, int G){
  int g = threadIdx.x;
  if(g < G){
    float e0 = e_acc[2*g], e1 = e_acc[2*g+1];
    out[g] = e0+e1;
    out[G + 2*g] = e0;
    out[G + 2*g+1] = e1;
  }
}

extern "C" void kernel_launch(void* const* d_in, const int* in_sizes, int n_in,
                              void* d_out, int out_size, void* d_ws, size_t ws_size,
                              hipStream_t stream) {
  const float* positions  = (const float*)d_in[0];
  const float* node_attrs = (const float*)d_in[1];
  const float* shifts     = (const float*)d_in[2];
  const float* W_embed    = (const float*)d_in[3];
  const float* at_en      = (const float*)d_in[4];
  const float* W_r1       = (const float*)d_in[5];
  const float* W_r2       = (const float*)d_in[6];
  const float* W_mix      = (const float*)d_in[7];
  const float* W_prod     = (const float*)d_in[8];
  const float* w_ro       = (const float*)d_in[9];
  const int*   edge_index = (const int*)d_in[10];
  const int*   batch      = (const int*)d_in[11];

  int N = in_sizes[0]/3;
  int E = in_sizes[10]/2;
  int G = (out_size - 3*N)/3;

  float* out    = (float*)d_out;
  float* A      = (float*)d_ws;                 // N*1024
  float* h      = A + (size_t)N*1024;           // N*64
  float* W2T    = h + (size_t)N*64;             // 4096
  float* eacc   = W2T + 4096;                   // 2G
  int*   deg    = (int*)(eacc + 2*G);           // N
  int*   rowptr = deg + N;                      // N+1
  int*   cursor = rowptr + N + 1;               // N
  int*   elist  = cursor + N;                   // E

  hipMemsetAsync(d_out, 0, (size_t)out_size*sizeof(float), stream);
  hipMemsetAsync(eacc, 0, (size_t)2*G*sizeof(float), stream);
  hipMemsetAsync(deg, 0, (size_t)N*sizeof(int), stream);

  embed_k<<<N, 64, 0, stream>>>(node_attrs, W_embed, at_en, batch, h, eacc, N);
  tr_k<<<16, 256, 0, stream>>>(W_r2, W2T);
  count_k<<<(E+255)/256, 256, 0, stream>>>(positions, shifts, edge_index, deg, E);
  scan_k<<<1, 256, 0, stream>>>(deg, rowptr, cursor, N);
  scatter_k<<<(E+255)/256, 256, 0, stream>>>(positions, shifts, edge_index, cursor, elist, E);
  fwd_fused<<<2048, 256, 0, stream>>>(positions, shifts, edge_index, h, W_r1, W_r2, rowptr, elist, A, N, E);
  node_k<<<512, 256, 0, stream>>>(A, W_mix, W_prod, w_ro, batch, eacc, N);
  bwd_fused<<<1024, 256, 0, stream>>>(positions, shifts, edge_index, h, W_r1, W_r2, W2T, A, rowptr, elist, out + 3*G, N, E);
  fin_k<<<1, 64, 0, stream>>>(eacc, out, G);
}

// Round 5
// 385.620 us; speedup vs baseline: 1.8499x; 1.3568x over previous
//
#include <hip/hip_runtime.h>
#include <cmath>

#define RMAXF 5.0f
#define INV_AVG (1.0f/16.0f)
#define SQ4PI 3.5449077018110318f
#define NPTS 4096
#define TAB_SCALE ((float)(NPTS-1)/RMAXF)

// Real sph harmonics l=0..3 (times sqrt(4pi)) of unit vector (x,y,z)
__device__ __forceinline__ void sph16(float x, float y, float z, float* Y){
  float x2=x*x, y2=y*y, z2=z*z;
  Y[0]=SQ4PI*0.28209479177387814f;
  Y[1]=SQ4PI*0.4886025119029199f*y;
  Y[2]=SQ4PI*0.4886025119029199f*z;
  Y[3]=SQ4PI*0.4886025119029199f*x;
  Y[4]=SQ4PI*1.0925484305920792f*x*y;
  Y[5]=SQ4PI*1.0925484305920792f*y*z;
  Y[6]=SQ4PI*0.31539156525252005f*(3.f*z2-1.f);
  Y[7]=SQ4PI*1.0925484305920792f*x*z;
  Y[8]=SQ4PI*0.5462742152960396f*(x2-y2);
  Y[9]=SQ4PI*0.5900435899266435f*y*(3.f*x2-y2);
  Y[10]=SQ4PI*2.890611442640554f*x*y*z;
  Y[11]=SQ4PI*0.4570457994644658f*y*(5.f*z2-1.f);
  Y[12]=SQ4PI*0.3731763325901154f*z*(5.f*z2-3.f);
  Y[13]=SQ4PI*0.4570457994644658f*x*(5.f*z2-1.f);
  Y[14]=SQ4PI*1.445305721320277f*z*(x2-y2);
  Y[15]=SQ4PI*0.5900435899266435f*x*(x2-3.f*y2);
}

// radial basis ef[8] = bess*fcut and d(ef)/dr (table builder only)
__device__ __forceinline__ void radial(float r, float* ef, float* def){
  const float PI_ = 3.14159265358979323846f;
  const float c = 0.6324555320336759f; // sqrt(2/5)
  float xr = r*(1.0f/RMAXF);
  float x2=xr*xr, x3=x2*xr, x5=x3*x2, x6=x5*xr, x7=x6*xr, x8=x7*xr;
  float fcut = 1.f - 28.f*x6 + 48.f*x7 - 21.f*x8;
  float om = 1.f - xr;
  float dfcut = -168.f*x5*om*om*(1.0f/RMAXF);
  float invr = 1.f/r;
  #pragma unroll
  for(int n=1;n<=8;n++){
    float a = (float)n*PI_*(1.0f/RMAXF);
    float ar = a*r;
    float s, co;
    sincosf(ar, &s, &co);
    float b = c*s*invr;
    ef[n-1] = b*fcut;
    def[n-1] = c*(a*co - s*invr)*invr*fcut + b*dfcut;
  }
}

// ---------------- build radial tables: w(r), dw/dr(r), 64 channels --------
__global__ __launch_bounds__(64) void tab_k(
    const float* __restrict__ W_r1, const float* __restrict__ W_r2,
    float* __restrict__ w_tab, float* __restrict__ dw_tab)
{
  __shared__ float s_sil[64], s_ds[64];
  int p = blockIdx.x, lane = threadIdx.x;
  float r = fmaxf((float)p * (RMAXF/(float)(NPTS-1)), 1e-6f);
  float ef[8], def[8];
  radial(r, ef, def);
  float t = 0.f, dt = 0.f;
  #pragma unroll
  for(int j=0;j<8;j++){ t += ef[j]*W_r1[j*64+lane]; dt += def[j]*W_r1[j*64+lane]; }
  float sig = 1.f/(1.f+expf(-t));
  s_sil[lane] = t*sig;
  s_ds[lane]  = sig*(1.f + t*(1.f-sig))*dt;
  __syncthreads();
  float w = 0.f, dw = 0.f;
  for(int j=0;j<64;j++){
    w  += s_sil[j]*W_r2[j*64+lane];
    dw += s_ds[j] *W_r2[j*64+lane];
  }
  w_tab[p*64+lane]  = w;
  dw_tab[p*64+lane] = dw;
}

// ---------------- node embed: h = attrs @ W_embed, e0 atomic per graph ----
__global__ __launch_bounds__(64) void embed_k(
    const float* __restrict__ attrs, const float* __restrict__ W_embed,
    const float* __restrict__ ae, const int* __restrict__ batch,
    float* __restrict__ h, float* __restrict__ e_acc, int N)
{
  int n = blockIdx.x;
  if(n >= N) return;
  int k = threadIdx.x;
  float acc = 0.f;
  #pragma unroll
  for(int s=0;s<10;s++) acc += attrs[n*10+s]*W_embed[s*64+k];
  h[(size_t)n*64+k] = acc;
  if(k==0){
    float e0 = 0.f;
    #pragma unroll
    for(int s=0;s<10;s++) e0 += attrs[n*10+s]*ae[s];
    atomicAdd(&e_acc[batch[n]*2+0], e0);
  }
}

// ---------------- CSR build over surviving edges (r < RMAX), key = recv ---
__global__ __launch_bounds__(256) void count_k(
    const float* __restrict__ pos, const float* __restrict__ shifts,
    const int* __restrict__ eidx, int* __restrict__ deg, int E)
{
  int e = blockIdx.x*256 + threadIdx.x;
  if(e >= E) return;
  int snd = eidx[e], rcv = eidx[E+e];
  float vx = pos[rcv*3+0]-pos[snd*3+0]+shifts[e*3+0];
  float vy = pos[rcv*3+1]-pos[snd*3+1]+shifts[e*3+1];
  float vz = pos[rcv*3+2]-pos[snd*3+2]+shifts[e*3+2];
  float r2 = vx*vx+vy*vy+vz*vz + 1e-12f;
  if(r2 < RMAXF*RMAXF) atomicAdd(&deg[rcv], 1);
}

__global__ __launch_bounds__(256) void scan_k(
    const int* __restrict__ deg, int* __restrict__ rowptr,
    int* __restrict__ cursor, int N)
{
  __shared__ int part[256];
  int tid = threadIdx.x;
  int chunk = (N + 255) / 256;
  int begin = tid*chunk, end = begin+chunk < N ? begin+chunk : N;
  int s = 0;
  for(int i=begin;i<end;i++) s += deg[i];
  part[tid] = s;
  __syncthreads();
  for(int off=1; off<256; off<<=1){
    int t = (tid >= off) ? part[tid-off] : 0;
    __syncthreads();
    part[tid] += t;
    __syncthreads();
  }
  int run = part[tid] - s;   // exclusive prefix of this thread's chunk
  for(int i=begin;i<end;i++){
    rowptr[i] = run; cursor[i] = run; run += deg[i];
  }
  if(tid == 255) rowptr[N] = part[255];
}

__global__ __launch_bounds__(256) void scatter_k(
    const float* __restrict__ pos, const float* __restrict__ shifts,
    const int* __restrict__ eidx, int* __restrict__ cursor,
    int* __restrict__ elist, int E)
{
  int e = blockIdx.x*256 + threadIdx.x;
  if(e >= E) return;
  int snd = eidx[e], rcv = eidx[E+e];
  float vx = pos[rcv*3+0]-pos[snd*3+0]+shifts[e*3+0];
  float vy = pos[rcv*3+1]-pos[snd*3+1]+shifts[e*3+1];
  float vz = pos[rcv*3+2]-pos[snd*3+2]+shifts[e*3+2];
  float r2 = vx*vx+vy*vy+vz*vz + 1e-12f;
  if(r2 < RMAXF*RMAXF){
    int p = atomicAdd(&cursor[rcv], 1);
    elist[p] = e;
  }
}

// ---------------- edge forward: one wave per node, table lookup ----------
__global__ __launch_bounds__(256) void fwd_tab(
    const float* __restrict__ pos, const float* __restrict__ shifts,
    const int* __restrict__ eidx, const float* __restrict__ h,
    const float* __restrict__ w_tab,
    const int* __restrict__ rowptr, const int* __restrict__ elist,
    float* __restrict__ A, int N, int E)
{
  int tid = threadIdx.x, ws4 = tid >> 6, lane = tid & 63;
  int n = blockIdx.x*4 + ws4;
  if(n >= N) return;
  int beg = rowptr[n], endp = rowptr[n+1];
  float acc[16];
  #pragma unroll
  for(int lm=0;lm<16;lm++) acc[lm] = 0.f;
  float px = pos[n*3+0], py = pos[n*3+1], pz = pos[n*3+2];
  for(int idx=beg; idx<endp; idx++){
    int e = elist[idx];
    int snd = eidx[e];
    float vx = px - pos[snd*3+0] + shifts[e*3+0];
    float vy = py - pos[snd*3+1] + shifts[e*3+1];
    float vz = pz - pos[snd*3+2] + shifts[e*3+2];
    float r = sqrtf(vx*vx+vy*vy+vz*vz + 1e-12f);
    float invr = 1.f/r;
    float Y[16]; sph16(vx*invr, vy*invr, vz*invr, Y);
    float rs = r*TAB_SCALE;
    int i0 = (int)rs; i0 = i0 < NPTS-2 ? i0 : NPTS-2;
    float fr = rs - (float)i0;
    const float* t0 = w_tab + i0*64 + lane;
    float w0 = t0[0], w1 = t0[64];
    float w = w0 + fr*(w1-w0);
    float wh = w * h[(size_t)snd*64+lane] * INV_AVG;
    #pragma unroll
    for(int lm=0;lm<16;lm++) acc[lm] += wh*Y[lm];
  }
  float* Ab = A + (size_t)n*1024 + lane;
  #pragma unroll
  for(int lm=0;lm<16;lm++) Ab[lm*64] = acc[lm];
}

// ---------------- node: Am, s, B, node_e, and gA (in-place over A) --------
__global__ __launch_bounds__(256) void node_k(
    float* __restrict__ A,              // [N][16][64], overwritten with gA
    const float* __restrict__ W_mix,    // [4][64][64]
    const float* __restrict__ W_prod,   // [3][64]
    const float* __restrict__ w_ro,     // [64]
    const int* __restrict__ batch, float* __restrict__ e_acc, int N)
{
  __shared__ float sW[16384];
  __shared__ float sA[1024];
  __shared__ float sG[1024];
  __shared__ float sS[4][64];
  __shared__ float sSf[64];
  __shared__ float sA0[64];

  const int tid = threadIdx.x;
  const int c = tid & 63;
  const int lmg = tid >> 6;
  const int swz = (c & 7) << 2;

  for(int i = tid; i < 16384; i += 256){
    int l = i >> 12, k = (i >> 6) & 63, cc = i & 63;
    sW[l*4096 + cc*64 + (k ^ ((cc&7)<<2))] = W_mix[i];
  }

  const float wp0 = W_prod[c], wp1 = W_prod[64+c], wp2 = W_prod[128+c], wr = w_ro[c];
  const int lA = (lmg==0)?0:((lmg<3)?2:3);
  const int lB = (lmg==0)?1:((lmg==1)?2:3);
  const float* wBa = &sW[lA*4096 + c*64];
  const float* wBb = &sW[lB*4096 + c*64];
  const float* aB0 = &sA[(lmg*4+0)*64];
  const float* aB1 = &sA[(lmg*4+1)*64];
  const float* aB2 = &sA[(lmg*4+2)*64];
  const float* aB3 = &sA[(lmg*4+3)*64];
  float* gB0 = &sG[(lmg*4+0)*64];
  float* gB1 = &sG[(lmg*4+1)*64];
  float* gB2 = &sG[(lmg*4+2)*64];
  float* gB3 = &sG[(lmg*4+3)*64];

  for(int n = blockIdx.x; n < N; n += gridDim.x){
    reinterpret_cast<float4*>(sA)[tid] =
        reinterpret_cast<const float4*>(A + (size_t)n*1024)[tid];
    __syncthreads();

    float am0=0.f, am1=0.f, am2=0.f, am3=0.f;
    #pragma unroll
    for(int kb=0; kb<16; kb++){
      int ko = (kb*4) ^ swz;
      float4 wa = *reinterpret_cast<const float4*>(wBa + ko);
      float4 wb = *reinterpret_cast<const float4*>(wBb + ko);
      float4 a0 = *reinterpret_cast<const float4*>(aB0 + kb*4);
      float4 a1 = *reinterpret_cast<const float4*>(aB1 + kb*4);
      float4 a2 = *reinterpret_cast<const float4*>(aB2 + kb*4);
      float4 a3 = *reinterpret_cast<const float4*>(aB3 + kb*4);
      am0 += a0.x*wa.x + a0.y*wa.y + a0.z*wa.z + a0.w*wa.w;
      am1 += a1.x*wb.x + a1.y*wb.y + a1.z*wb.z + a1.w*wb.w;
      am2 += a2.x*wb.x + a2.y*wb.y + a2.z*wb.z + a2.w*wb.w;
      am3 += a3.x*wb.x + a3.y*wb.y + a3.z*wb.z + a3.w*wb.w;
    }
    float part = am0*am0 + am1*am1 + am2*am2 + am3*am3;
    sS[lmg][c] = part;
    __syncthreads();
    if(lmg==0){
      sSf[c] = sS[0][c]+sS[1][c]+sS[2][c]+sS[3][c];
      sA0[c] = am0;
    }
    __syncthreads();
    float s_ = sSf[c], a0_ = sA0[c];
    if(lmg==0){
      float B = wp0*a0_ + wp1*s_ + wp2*a0_*s_;
      float v = B*wr;
      #pragma unroll
      for(int off=32; off; off>>=1) v += __shfl_xor(v, off, 64);
      if(c==0) atomicAdd(&e_acc[batch[n]*2+1], v);
    }
    float gs = wr*(wp1 + wp2*a0_);
    {
      float g0 = gs*2.f*am0;
      if(lmg==0) g0 += wr*(wp0 + wp2*s_);
      gB0[c] = g0;
      gB1[c] = gs*2.f*am1;
      gB2[c] = gs*2.f*am2;
      gB3[c] = gs*2.f*am3;
    }
    __syncthreads();

    float ga0=0.f, ga1=0.f, ga2=0.f, ga3=0.f;
    #pragma unroll
    for(int cb=0; cb<16; cb++){
      float g0[4], g1[4], g2[4], g3[4];
      *reinterpret_cast<float4*>(g0) = *reinterpret_cast<const float4*>(gB0 + cb*4);
      *reinterpret_cast<float4*>(g1) = *reinterpret_cast<const float4*>(gB1 + cb*4);
      *reinterpret_cast<float4*>(g2) = *reinterpret_cast<const float4*>(gB2 + cb*4);
      *reinterpret_cast<float4*>(g3) = *reinterpret_cast<const float4*>(gB3 + cb*4);
      #pragma unroll
      for(int j=0;j<4;j++){
        int cc = cb*4 + j;
        int sidx = cc*64 + (c ^ ((cc&7)<<2));
        float wa = sW[lA*4096 + sidx];
        float wb = sW[lB*4096 + sidx];
        ga0 += wa*g0[j];
        ga1 += wb*g1[j];
        ga2 += wb*g2[j];
        ga3 += wb*g3[j];
      }
    }
    float* dst = A + (size_t)n*1024 + (size_t)lmg*256 + c;
    dst[0]   = ga0;
    dst[64]  = ga1;
    dst[128] = ga2;
    dst[192] = ga3;
    __syncthreads();
  }
}

// ---------------- edge backward: one wave per node, table lookup ----------
__global__ __launch_bounds__(256) void bwd_tab(
    const float* __restrict__ pos, const float* __restrict__ shifts,
    const int* __restrict__ eidx, const float* __restrict__ h,
    const float* __restrict__ w_tab, const float* __restrict__ dw_tab,
    const float* __restrict__ gA,
    const int* __restrict__ rowptr, const int* __restrict__ elist,
    float* __restrict__ forces, int N, int E)
{
  int tid = threadIdx.x, ws4 = tid >> 6, lane = tid & 63;
  int n = blockIdx.x*4 + ws4;
  if(n >= N) return;
  int beg = rowptr[n], endp = rowptr[n+1];
  if(beg == endp) return;
  float gm[16];
  {
    const float* gb = gA + (size_t)n*1024 + lane;
    #pragma unroll
    for(int lm=0;lm<16;lm++) gm[lm] = gb[lm*64]*INV_AVG;
  }
  float px = pos[n*3+0], py = pos[n*3+1], pz = pos[n*3+2];
  float fx=0.f, fy=0.f, fz=0.f;
  const float c1=0.4886025119029199f, c2=1.0925484305920792f, c3=0.31539156525252005f;
  const float c4=0.5462742152960396f, c5=0.5900435899266435f, c6=2.890611442640554f;
  const float c7=0.4570457994644658f, c8=0.3731763325901154f, c9=1.445305721320277f;

  for(int idx=beg; idx<endp; idx++){
    int e = elist[idx];
    int snd = eidx[e];
    float vx = px - pos[snd*3+0] + shifts[e*3+0];
    float vy = py - pos[snd*3+1] + shifts[e*3+1];
    float vz = pz - pos[snd*3+2] + shifts[e*3+2];
    float r = sqrtf(vx*vx+vy*vy+vz*vz + 1e-12f);
    float invr = 1.f/r;
    float x=vx*invr, y=vy*invr, z=vz*invr;
    float Y[16]; sph16(x,y,z,Y);
    float rs = r*TAB_SCALE;
    int i0 = (int)rs; i0 = i0 < NPTS-2 ? i0 : NPTS-2;
    float fr = rs - (float)i0;
    const float* t0 = w_tab  + i0*64 + lane;
    const float* d0 = dw_tab + i0*64 + lane;
    float w    = t0[0] + fr*(t0[64]-t0[0]);
    float dwdr = d0[0] + fr*(d0[64]-d0[0]);
    float hk = h[(size_t)snd*64+lane];
    float wh = w*hk;
    // g_w[k] = hk * sum_lm gm[k][lm]*Y[lm]
    float gw = 0.f;
    #pragma unroll
    for(int lm=0;lm<16;lm++) gw += gm[lm]*Y[lm];
    gw *= hk;
    // dY/du contracted with gm per lane, then one butterfly per component
    float x2=x*x, y2=y*y, z2=z*z;
    float fz1 = 5.f*z2-1.f;
    float gxp = c1*gm[3] + c2*(y*gm[4] + z*gm[7]) + 2.f*c4*x*gm[8]
              + 6.f*c5*x*y*gm[9] + c6*y*z*gm[10] + c7*fz1*gm[13]
              + 2.f*c9*x*z*gm[14] + 3.f*c5*(x2-y2)*gm[15];
    float gyp = c1*gm[1] + c2*(x*gm[4] + z*gm[5]) - 2.f*c4*y*gm[8]
              + 3.f*c5*(x2-y2)*gm[9] + c6*x*z*gm[10] + c7*fz1*gm[11]
              - 2.f*c9*y*z*gm[14] - 6.f*c5*x*y*gm[15];
    float gzp = c1*gm[2] + c2*(y*gm[5] + x*gm[7]) + 6.f*c3*z*gm[6]
              + c6*x*y*gm[10] + 10.f*c7*y*z*gm[11] + c8*(15.f*z2-3.f)*gm[12]
              + 10.f*c7*x*z*gm[13] + c9*(x2-y2)*gm[14];
    float gx = gxp*wh*SQ4PI, gy = gyp*wh*SQ4PI, gz = gzp*wh*SQ4PI;
    // radial path: dE/dr partial = g_w[k]*dw/dr[k], reduced over k
    float grp = gw*dwdr;
    #pragma unroll
    for(int off=32; off; off>>=1){
      gx  += __shfl_xor(gx,  off, 64);
      gy  += __shfl_xor(gy,  off, 64);
      gz  += __shfl_xor(gz,  off, 64);
      grp += __shfl_xor(grp, off, 64);
    }
    float udot = x*gx + y*gy + z*gz;
    float gvx = grp*x + (gx - udot*x)*invr;
    float gvy = grp*y + (gy - udot*y)*invr;
    float gvz = grp*z + (gz - udot*z)*invr;
    fx -= gvx; fy -= gvy; fz -= gvz;
    if(lane==0){
      atomicAdd(&forces[snd*3+0],  gvx);
      atomicAdd(&forces[snd*3+1],  gvy);
      atomicAdd(&forces[snd*3+2],  gvz);
    }
  }
  if(lane==0){
    atomicAdd(&forces[n*3+0], fx);
    atomicAdd(&forces[n*3+1], fy);
    atomicAdd(&forces[n*3+2], fz);
  }
}

// ---------------- finalize ---------------------------------------------
__global__ void fin_k(const float* __restrict__ e_acc, float* __restrict__ out, int G){
  int g = threadIdx.x;
  if(g < G){
    float e0 = e_acc[2*g], e1 = e_acc[2*g+1];
    out[g] = e0+e1;
    out[G + 2*g] = e0;
    out[G + 2*g+1] = e1;
  }
}

extern "C" void kernel_launch(void* const* d_in, const int* in_sizes, int n_in,
                              void* d_out, int out_size, void* d_ws, size_t ws_size,
                              hipStream_t stream) {
  const float* positions  = (const float*)d_in[0];
  const float* node_attrs = (const float*)d_in[1];
  const float* shifts     = (const float*)d_in[2];
  const float* W_embed    = (const float*)d_in[3];
  const float* at_en      = (const float*)d_in[4];
  const float* W_r1       = (const float*)d_in[5];
  const float* W_r2       = (const float*)d_in[6];
  const float* W_mix      = (const float*)d_in[7];
  const float* W_prod     = (const float*)d_in[8];
  const float* w_ro       = (const float*)d_in[9];
  const int*   edge_index = (const int*)d_in[10];
  const int*   batch      = (const int*)d_in[11];

  int N = in_sizes[0]/3;
  int E = in_sizes[10]/2;
  int G = (out_size - 3*N)/3;

  float* out    = (float*)d_out;
  float* A      = (float*)d_ws;                 // N*1024
  float* h      = A + (size_t)N*1024;           // N*64
  float* w_tab  = h + (size_t)N*64;             // NPTS*64
  float* dw_tab = w_tab + (size_t)NPTS*64;      // NPTS*64
  float* eacc   = dw_tab + (size_t)NPTS*64;     // 2G
  int*   deg    = (int*)(eacc + 2*G);           // N
  int*   rowptr = deg + N;                      // N+1
  int*   cursor = rowptr + N + 1;               // N
  int*   elist  = cursor + N;                   // E

  hipMemsetAsync(d_out, 0, (size_t)out_size*sizeof(float), stream);
  hipMemsetAsync(eacc, 0, (size_t)2*G*sizeof(float), stream);
  hipMemsetAsync(deg, 0, (size_t)N*sizeof(int), stream);

  embed_k<<<N, 64, 0, stream>>>(node_attrs, W_embed, at_en, batch, h, eacc, N);
  tab_k<<<NPTS, 64, 0, stream>>>(W_r1, W_r2, w_tab, dw_tab);
  count_k<<<(E+255)/256, 256, 0, stream>>>(positions, shifts, edge_index, deg, E);
  scan_k<<<1, 256, 0, stream>>>(deg, rowptr, cursor, N);
  scatter_k<<<(E+255)/256, 256, 0, stream>>>(positions, shifts, edge_index, cursor, elist, E);
  fwd_tab<<<(N+3)/4, 256, 0, stream>>>(positions, shifts, edge_index, h, w_tab, rowptr, elist, A, N, E);
  node_k<<<512, 256, 0, stream>>>(A, W_mix, W_prod, w_ro, batch, eacc, N);
  bwd_tab<<<(N+3)/4, 256, 0, stream>>>(positions, shifts, edge_index, h, w_tab, dw_tab, A, rowptr, elist, out + 3*G, N, E);
  fin_k<<<1, 64, 0, stream>>>(eacc, out, G);
}